// Round 10
// baseline (628.325 us; speedup 1.0000x reference)
//
#include <hip/hip_runtime.h>
#include <cstdint>

typedef _Float16 half8 __attribute__((ext_vector_type(8)));
typedef float f32x4 __attribute__((ext_vector_type(4)));

#define NNODES 80000
#define NEDGES 1280000
#define INDIM 32
#define EDIM 16
#define HID 64
#define HID2 128
#define DEPTH 4
#define BN_EPS 1e-5f
#define LN_EPS 1e-5f
#define NB 313         // ceil(80000/256)
#define NPX 10000      // nodes per XCD partition (80000/8)
#define EPS 10000      // edges per slice (1280000/128)

union U16x8 { uint4 v; _Float16 h[8]; };
union U16x4 { uint2 v; _Float16 h[4]; };

// h = relu(x @ Wx + bx) -> f16; one wave per node, lane = out channel
__global__ __launch_bounds__(256) void k_node_embed(
    const float* __restrict__ x, const float* __restrict__ Wx,
    const float* __restrict__ bx, _Float16* __restrict__ h16) {
    int gw = (blockIdx.x * 256 + threadIdx.x) >> 6;
    int lane = threadIdx.x & 63;
    if (gw >= NNODES) return;
    float xv = (lane < INDIM) ? x[(size_t)gw * INDIM + lane] : 0.f;
    float acc = bx[lane];
#pragma unroll
    for (int k = 0; k < INDIM; k++)
        acc = fmaf(__shfl(xv, k, 64), Wx[k * HID + lane], acc);
    h16[(size_t)gw * HID + lane] = (_Float16)fmaxf(acc, 0.f);
}

// one-time: transpose+convert weights to f16. w1T[l][n(128)][k(64)], w2T[l][n(64)][k(128)]
__global__ __launch_bounds__(256) void k_prep(
    const float* __restrict__ W1, const float* __restrict__ W2,
    _Float16* __restrict__ w1T, _Float16* __restrict__ w2T) {
    int id = blockIdx.x * 256 + threadIdx.x;
    if (id < DEPTH * 128 * 64) {
        int l = id / 8192, r = id % 8192, n = r / 64, k = r % 64;
        w1T[id] = (_Float16)W1[(size_t)l * 8192 + k * 128 + n];
    } else {
        int idx = id - DEPTH * 128 * 64;
        int l = idx / 8192, r = idx % 8192, n = r / 128, k = r % 128;
        w2T[idx] = (_Float16)W2[(size_t)l * 8192 + k * 64 + n];
    }
}

// XCD-partitioned histogram: block s*8+r handles edge slice s, node range r.
__global__ __launch_bounds__(256) void k_hist(const int* __restrict__ col,
                                              int* __restrict__ deg) {
    int xcd = blockIdx.x & 7;
    int slice = blockIdx.x >> 3;
    int base = slice * EPS;
    int lo = xcd * NPX;
    const int4* c4 = (const int4*)(col + base);
    for (int i = threadIdx.x; i < EPS / 4; i += 256) {
        int4 c = c4[i];
#pragma unroll
        for (int u = 0; u < 4; u++) {
            int cc = (&c.x)[u];
            if ((unsigned)(cc - lo) < (unsigned)NPX) atomicAdd(&deg[cc], 1);
        }
    }
}

__global__ __launch_bounds__(256) void k_scan1(const int* __restrict__ deg, int* __restrict__ bsum) {
    __shared__ int s[256];
    int i = blockIdx.x * 256 + threadIdx.x;
    int v = (i < NNODES) ? deg[i] : 0;
    s[threadIdx.x] = v;
    __syncthreads();
    for (int o = 128; o > 0; o >>= 1) {
        if (threadIdx.x < o) s[threadIdx.x] += s[threadIdx.x + o];
        __syncthreads();
    }
    if (threadIdx.x == 0) bsum[blockIdx.x] = s[0];
}

__global__ __launch_bounds__(512) void k_scan2(const int* __restrict__ bsum, int* __restrict__ boff) {
    __shared__ int s[512];
    int t = threadIdx.x;
    s[t] = (t < NB) ? bsum[t] : 0;
    __syncthreads();
    for (int o = 1; o < 512; o <<= 1) {
        int v = (t >= o) ? s[t - o] : 0;
        __syncthreads();
        s[t] += v;
        __syncthreads();
    }
    if (t < NB) boff[t] = (t == 0) ? 0 : s[t - 1];
}

__global__ __launch_bounds__(256) void k_scan3(const int* __restrict__ deg,
                                               const int* __restrict__ boff,
                                               int* __restrict__ row_off) {
    __shared__ int s[256];
    int i = blockIdx.x * 256 + threadIdx.x;
    int t = threadIdx.x;
    int v = (i < NNODES) ? deg[i] : 0;
    s[t] = v;
    __syncthreads();
    for (int o = 1; o < 256; o <<= 1) {
        int u = (t >= o) ? s[t - o] : 0;
        __syncthreads();
        s[t] += u;
        __syncthreads();
    }
    int incl = s[t];
    if (i < NNODES) row_off[i] = boff[blockIdx.x] + incl - v;
    if (i == NNODES - 1) row_off[NNODES] = boff[blockIdx.x] + incl;
}

__global__ __launch_bounds__(256) void k_copy(const int* __restrict__ src, int* __restrict__ dst) {
    int i = blockIdx.x * 256 + threadIdx.x;
    if (i < NNODES) dst[i] = src[i];
}

// XCD-partitioned scatter: cursor atomics and sre line writes stay XCD-local.
__global__ __launch_bounds__(256) void k_scatter(
    const int* __restrict__ row, const int* __restrict__ col,
    int* __restrict__ cursor, uint2* __restrict__ sre) {
    int xcd = blockIdx.x & 7;
    int slice = blockIdx.x >> 3;
    int base = slice * EPS;
    int lo = xcd * NPX;
    const int4* c4 = (const int4*)(col + base);
    for (int i = threadIdx.x; i < EPS / 4; i += 256) {
        int4 c = c4[i];
        int e0 = base + i * 4;
#pragma unroll
        for (int u = 0; u < 4; u++) {
            int cc = (&c.x)[u];
            if ((unsigned)(cc - lo) < (unsigned)NPX) {
                int e = e0 + u;
                int pos = atomicAdd(&cursor[cc], 1);
                sre[pos] = make_uint2((unsigned)row[e], (unsigned)e);
            }
        }
    }
}

// ea[pos] = relu(edge_attr[sre[pos].y] @ We + be), f16, CSR order. Also emits srow.
// MFMA with SWAPPED operands: D = We_frag x edge_frag -> lane holds 4 CONTIGUOUS
// channels of one edge -> packed 8B direct-global stores. No O-transpose phase.
__global__ __launch_bounds__(256) void k_edge_embed(
    const float* __restrict__ eat, const uint2* __restrict__ sre,
    const float* __restrict__ We, const float* __restrict__ be,
    _Float16* __restrict__ eas, int* __restrict__ srow) {
    __shared__ __align__(16) unsigned char lds[4][5120];   // 64 edges x 80B per wave
    int tid = threadIdx.x;
    int w = tid >> 6, lane = tid & 63;
    unsigned char* A = lds[w];
    int ebase = blockIdx.x * 256 + w * 64;
    int b = lane >> 4, c = lane & 15;
    // We fragments (A operand: rows = channels t*16+c, k-octet b; zero for b>=2)
    half8 wf[4];
#pragma unroll
    for (int t = 0; t < 4; t++) {
        half8 v = {};
        if (b < 2) {
#pragma unroll
            for (int j = 0; j < 8; j++) {
                int k = b * 8 + j;
                v[j] = (_Float16)We[k * HID + t * 16 + c];
            }
        }
        wf[t] = v;
    }
    // bias for channels t*16 + b*4 + 0..3
    float4 bias4[4];
#pragma unroll
    for (int t = 0; t < 4; t++) bias4[t] = *(const float4*)(be + t * 16 + b * 4);
    // gather + stage edge attrs (f16) into LDS
    uint2 se = sre[ebase + lane];
    srow[ebase + lane] = (int)se.x;
    const float4* ar = (const float4*)(eat + (size_t)se.y * EDIM);
    float4 a0 = ar[0], a1 = ar[1], a2 = ar[2], a3 = ar[3];
    U16x8 lo, hi;
    lo.h[0] = (_Float16)a0.x; lo.h[1] = (_Float16)a0.y;
    lo.h[2] = (_Float16)a0.z; lo.h[3] = (_Float16)a0.w;
    lo.h[4] = (_Float16)a1.x; lo.h[5] = (_Float16)a1.y;
    lo.h[6] = (_Float16)a1.z; lo.h[7] = (_Float16)a1.w;
    hi.h[0] = (_Float16)a2.x; hi.h[1] = (_Float16)a2.y;
    hi.h[2] = (_Float16)a2.z; hi.h[3] = (_Float16)a2.w;
    hi.h[4] = (_Float16)a3.x; hi.h[5] = (_Float16)a3.y;
    hi.h[6] = (_Float16)a3.z; hi.h[7] = (_Float16)a3.w;
    *(uint4*)(A + lane * 80) = lo.v;
    *(uint4*)(A + lane * 80 + 16) = hi.v;
    __syncthreads();
    // edge fragments (B operand: cols = edges it*16+c, k-octet b; zero for b>=2)
    half8 ef[4];
#pragma unroll
    for (int it = 0; it < 4; it++) {
        half8 z = {};
        ef[it] = (b < 2) ? *(const half8*)(A + (it * 16 + c) * 80 + b * 16) : z;
    }
    // MFMA + packed direct-global epilogue
#pragma unroll
    for (int it = 0; it < 4; it++) {
        int edge = ebase + it * 16 + c;
        _Float16* dst = eas + (size_t)edge * HID + b * 4;
#pragma unroll
        for (int t = 0; t < 4; t++) {
            f32x4 acc = {0.f, 0.f, 0.f, 0.f};
            acc = __builtin_amdgcn_mfma_f32_16x16x32_f16(wf[t], ef[it], acc, 0, 0, 0);
            U16x4 pk;
#pragma unroll
            for (int r = 0; r < 4; r++)
                pk.h[r] = (_Float16)fmaxf(acc[r] + ((const float*)&bias4[t])[r], 0.f);
            *(uint2*)(dst + t * 16) = pk.v;
        }
    }
}

// zc[i] = (1+eps)*h[i] + sum_e relu(h[srow[e]] + ea[e]); vectorized:
// lane = (edge-slot = lane>>3, channel-octet = (lane&7)*8), uint4 loads
// -> 8 edges per VMEM instruction. Also zeroes bn_acc (block 0).
__global__ __launch_bounds__(256) void k_msg(
    const _Float16* __restrict__ h16, const int* __restrict__ row_off,
    const int* __restrict__ srow, const _Float16* __restrict__ eas,
    const float* __restrict__ epsp, _Float16* __restrict__ zc16,
    float* __restrict__ bn_acc) {
    if (blockIdx.x == 0) bn_acc[threadIdx.x] = 0.f;
    int gw = (blockIdx.x * 256 + threadIdx.x) >> 6;
    int lane = threadIdx.x & 63;
    if (gw >= NNODES) return;
    int grp = lane >> 3;          // edge slot 0..7
    int c8 = (lane & 7) * 8;      // channel octet base
    int beg = row_off[gw], end = row_off[gw + 1];
    float a[8] = {0.f, 0.f, 0.f, 0.f, 0.f, 0.f, 0.f, 0.f};
    int e = beg;
    for (; e + 16 <= end; e += 16) {
        int e0 = e + grp, e1 = e + 8 + grp;
        int j0 = srow[e0], j1 = srow[e1];
        U16x8 hv0, ev0, hv1, ev1;
        hv0.v = *(const uint4*)(h16 + (size_t)j0 * HID + c8);
        ev0.v = *(const uint4*)(eas + (size_t)e0 * HID + c8);
        hv1.v = *(const uint4*)(h16 + (size_t)j1 * HID + c8);
        ev1.v = *(const uint4*)(eas + (size_t)e1 * HID + c8);
#pragma unroll
        for (int q = 0; q < 8; q++) {
            a[q] += fmaxf((float)hv0.h[q] + (float)ev0.h[q], 0.f) +
                    fmaxf((float)hv1.h[q] + (float)ev1.h[q], 0.f);
        }
    }
    for (; e + 8 <= end; e += 8) {
        int e0 = e + grp;
        int j0 = srow[e0];
        U16x8 hv0, ev0;
        hv0.v = *(const uint4*)(h16 + (size_t)j0 * HID + c8);
        ev0.v = *(const uint4*)(eas + (size_t)e0 * HID + c8);
#pragma unroll
        for (int q = 0; q < 8; q++)
            a[q] += fmaxf((float)hv0.h[q] + (float)ev0.h[q], 0.f);
    }
    if (e < end) {   // tail 1..7 edges, masked
        int eidx = e + grp;
        bool valid = eidx < end;
        int ec = valid ? eidx : (NEDGES - 1);
        int j = srow[ec];
        U16x8 hv, ev;
        hv.v = *(const uint4*)(h16 + (size_t)j * HID + c8);
        ev.v = *(const uint4*)(eas + (size_t)ec * HID + c8);
        if (valid) {
#pragma unroll
            for (int q = 0; q < 8; q++)
                a[q] += fmaxf((float)hv.h[q] + (float)ev.h[q], 0.f);
        }
    }
#pragma unroll
    for (int q = 0; q < 8; q++) {
        a[q] += __shfl_xor(a[q], 8, 64);
        a[q] += __shfl_xor(a[q], 16, 64);
        a[q] += __shfl_xor(a[q], 32, 64);
    }
    if (grp == 0) {
        float epsl = 1.f + *epsp;
        U16x8 h0, o;
        h0.v = *(const uint4*)(h16 + (size_t)gw * HID + c8);
#pragma unroll
        for (int q = 0; q < 8; q++)
            o.h[q] = (_Float16)(epsl * (float)h0.h[q] + a[q]);
        *(uint4*)(zc16 + (size_t)gw * HID + c8) = o.v;
    }
}

// MFMA GEMM1: z1 = zc @ W1 + b1 (f16 in, f16 out) + BN sum/sumsq accumulation.
__global__ __launch_bounds__(256) void k_gemm1(
    const _Float16* __restrict__ zc16, const _Float16* __restrict__ w1Tl,
    const float* __restrict__ b1l, _Float16* __restrict__ z1,
    float* __restrict__ bn_acc) {
    __shared__ __align__(16) unsigned char At[64 * 128];    // 64 nodes x 64 f16, swizzled
    __shared__ __align__(16) unsigned char Bt[128 * 128];   // 128 cols x 64 f16, swizzled
    __shared__ float red[4][HID2][2];
    int tid = threadIdx.x;
    int nb = blockIdx.x * 64;
#pragma unroll
    for (int i = 0; i < 2; i++) {
        int id = tid + 256 * i;
        int node = id >> 3, c = id & 7;
        uint4 v = *(const uint4*)(zc16 + (size_t)(nb + node) * HID + c * 8);
        *(uint4*)(At + node * 128 + ((c ^ (node & 7)) << 4)) = v;
    }
#pragma unroll
    for (int i = 0; i < 4; i++) {
        int id = tid + 256 * i;
        int r = id >> 3, c = id & 7;
        uint4 v = *(const uint4*)(w1Tl + (size_t)r * HID + c * 8);
        *(uint4*)(Bt + r * 128 + ((c ^ (r & 7)) << 4)) = v;
    }
    __syncthreads();
    int lane = tid & 63, w = tid >> 6;
    int rl = lane & 15, b = lane >> 4;
    f32x4 acc[8];
#pragma unroll
    for (int t = 0; t < 8; t++) acc[t] = (f32x4){0.f, 0.f, 0.f, 0.f};
#pragma unroll
    for (int s = 0; s < 2; s++) {
        int arow = w * 16 + rl;
        half8 af = *(const half8*)(At + arow * 128 + (((s * 4 + b) ^ (rl & 7)) << 4));
#pragma unroll
        for (int t = 0; t < 8; t++) {
            int brow = t * 16 + rl;
            half8 bf = *(const half8*)(Bt + brow * 128 + (((s * 4 + b) ^ (rl & 7)) << 4));
            acc[t] = __builtin_amdgcn_mfma_f32_16x16x32_f16(af, bf, acc[t], 0, 0, 0);
        }
    }
#pragma unroll
    for (int t = 0; t < 8; t++) {
        int colg = t * 16 + rl;
        float bias = b1l[colg];
        float s = 0.f, q = 0.f;
#pragma unroll
        for (int r = 0; r < 4; r++) {
            float v = acc[t][r] + bias;
            int node = nb + w * 16 + b * 4 + r;
            z1[(size_t)node * HID2 + colg] = (_Float16)v;
            s += v;
            q = fmaf(v, v, q);
        }
        s += __shfl_xor(s, 16, 64); s += __shfl_xor(s, 32, 64);
        q += __shfl_xor(q, 16, 64); q += __shfl_xor(q, 32, 64);
        if (b == 0) { red[w][colg][0] = s; red[w][colg][1] = q; }
    }
    __syncthreads();
    int ch = tid & 127, which = tid >> 7;
    float tot = red[0][ch][which] + red[1][ch][which] + red[2][ch][which] + red[3][ch][which];
    atomicAdd(&bn_acc[which * HID2 + ch], tot);
}

// MFMA GEMM2 with inlined BN finalize: y = relu(BN(z1)); out = LN(y @ W2 + b2).
__global__ __launch_bounds__(256) void k_mlp2(
    const _Float16* __restrict__ z1, const float* __restrict__ bn_acc,
    const float* __restrict__ g1l, const float* __restrict__ bt1l,
    const _Float16* __restrict__ w2Tl, const float* __restrict__ b2l,
    const float* __restrict__ lngl, const float* __restrict__ lnbl,
    int last, _Float16* __restrict__ hout, float* __restrict__ fout) {
    __shared__ __align__(16) unsigned char Yt[64 * 256];   // 64 nodes x 128 f16, swizzled
    __shared__ __align__(16) unsigned char Wt[64 * 256];   // 64 cols x 128 f16, swizzled
    __shared__ float sbn[256];
    int tid = threadIdx.x;
    int nb = blockIdx.x * 64;
    if (tid < HID2) {   // inline BN finalize
        float inv_n = 1.f / (float)NNODES;
        float mu = bn_acc[tid] * inv_n;
        float ex2 = bn_acc[HID2 + tid] * inv_n;
        float rs = rsqrtf(ex2 - mu * mu + BN_EPS);
        float sc = g1l[tid] * rs;
        sbn[tid] = sc;
        sbn[HID2 + tid] = bt1l[tid] - mu * sc;
    }
#pragma unroll
    for (int i = 0; i < 4; i++) {
        int id = tid + 256 * i;
        int r = id >> 4, c = id & 15;
        uint4 v = *(const uint4*)(w2Tl + (size_t)r * HID2 + c * 8);
        *(uint4*)(Wt + r * 256 + ((c ^ (r & 7)) << 4)) = v;
    }
    __syncthreads();
#pragma unroll
    for (int i = 0; i < 4; i++) {
        int id = tid + 256 * i;
        int node = id >> 4, c = id & 15;
        U16x8 u, o;
        u.v = *(const uint4*)(z1 + (size_t)(nb + node) * HID2 + c * 8);
#pragma unroll
        for (int j = 0; j < 8; j++) {
            int chn = c * 8 + j;
            float y = fmaxf(fmaf((float)u.h[j], sbn[chn], sbn[HID2 + chn]), 0.f);
            o.h[j] = (_Float16)y;
        }
        *(uint4*)(Yt + node * 256 + ((c ^ (node & 7)) << 4)) = o.v;
    }
    __syncthreads();
    int lane = tid & 63, w = tid >> 6;
    int rl = lane & 15, b = lane >> 4;
    f32x4 acc[4];
#pragma unroll
    for (int t = 0; t < 4; t++) acc[t] = (f32x4){0.f, 0.f, 0.f, 0.f};
#pragma unroll
    for (int s = 0; s < 4; s++) {
        int arow = w * 16 + rl;
        half8 af = *(const half8*)(Yt + arow * 256 + (((s * 4 + b) ^ (rl & 7)) << 4));
#pragma unroll
        for (int t = 0; t < 4; t++) {
            int brow = t * 16 + rl;
            half8 bf = *(const half8*)(Wt + brow * 256 + (((s * 4 + b) ^ (rl & 7)) << 4));
            acc[t] = __builtin_amdgcn_mfma_f32_16x16x32_f16(af, bf, acc[t], 0, 0, 0);
        }
    }
    float a[4][4]; // [r][t]
#pragma unroll
    for (int t = 0; t < 4; t++) {
        float bias = b2l[t * 16 + rl];
#pragma unroll
        for (int r = 0; r < 4; r++) a[r][t] = acc[t][r] + bias;
    }
    float m[4], vv[4];
#pragma unroll
    for (int r = 0; r < 4; r++) {
        float s = (a[r][0] + a[r][1]) + (a[r][2] + a[r][3]);
        s += __shfl_xor(s, 1, 64); s += __shfl_xor(s, 2, 64);
        s += __shfl_xor(s, 4, 64); s += __shfl_xor(s, 8, 64);
        m[r] = s * (1.f / 64.f);
    }
#pragma unroll
    for (int r = 0; r < 4; r++) {
        float t0 = a[r][0] - m[r], t1 = a[r][1] - m[r];
        float t2 = a[r][2] - m[r], t3 = a[r][3] - m[r];
        float q = (t0 * t0 + t1 * t1) + (t2 * t2 + t3 * t3);
        q += __shfl_xor(q, 1, 64); q += __shfl_xor(q, 2, 64);
        q += __shfl_xor(q, 4, 64); q += __shfl_xor(q, 8, 64);
        vv[r] = rsqrtf(q * (1.f / 64.f) + LN_EPS);
    }
#pragma unroll
    for (int t = 0; t < 4; t++) {
        int colg = t * 16 + rl;
        float lg = lngl[colg], lb = lnbl[colg];
#pragma unroll
        for (int r = 0; r < 4; r++) {
            float o = (a[r][t] - m[r]) * vv[r] * lg + lb;
            size_t node = nb + w * 16 + b * 4 + r;
            if (last) {
                fout[node * HID + colg] = o;
            } else {
                hout[node * HID + colg] = (_Float16)fmaxf(o, 0.f);
            }
        }
    }
}

extern "C" void kernel_launch(void* const* d_in, const int* in_sizes, int n_in,
                              void* d_out, int out_size, void* d_ws, size_t ws_size,
                              hipStream_t stream) {
    const float* x   = (const float*)d_in[0];
    const int*   ei  = (const int*)d_in[1];
    const float* eat = (const float*)d_in[2];
    const float* Wx  = (const float*)d_in[3];
    const float* bx  = (const float*)d_in[4];
    const float* We  = (const float*)d_in[5];
    const float* be  = (const float*)d_in[6];
    const float* W1  = (const float*)d_in[7];
    const float* b1  = (const float*)d_in[8];
    const float* g1  = (const float*)d_in[9];
    const float* bt1 = (const float*)d_in[10];
    const float* W2  = (const float*)d_in[11];
    const float* b2  = (const float*)d_in[12];
    const float* eps = (const float*)d_in[13];
    const float* lng = (const float*)d_in[14];
    const float* lnb = (const float*)d_in[15];
    const int* row = ei;
    const int* col = ei + NEDGES;

    char* p = (char*)d_ws;
    auto alloc = [&](size_t bytes) -> char* {
        char* r = p;
        p += (bytes + 255) & ~(size_t)255;
        return r;
    };
    _Float16* h16  = (_Float16*)alloc((size_t)NNODES * HID * 2);
    _Float16* zc16 = (_Float16*)alloc((size_t)NNODES * HID * 2);
    _Float16* z1   = (_Float16*)alloc((size_t)NNODES * HID2 * 2);
    int* row_off   = (int*)alloc((size_t)(NNODES + 1) * 4);
    uint2* sre     = (uint2*)alloc((size_t)NEDGES * 8);
    int* srow      = (int*)alloc((size_t)NEDGES * 4);
    _Float16* eas  = (_Float16*)alloc((size_t)NEDGES * HID * 2);
    _Float16* w1T  = (_Float16*)alloc((size_t)DEPTH * 128 * 64 * 2);
    _Float16* w2T  = (_Float16*)alloc((size_t)DEPTH * 64 * 128 * 2);
    float* bn_acc  = (float*)alloc(256 * 4);
    // preamble-only buffers overlaid into z1's region (z1 first written in layer loop)
    int* cursor = (int*)z1;                       // NNODES ints
    int* bsum   = (int*)z1 + NNODES;              // NB ints
    int* boff   = bsum + NB;                      // NB ints
    (void)ws_size; (void)in_sizes; (void)n_in; (void)out_size;

    // ---- one-time: embeds + XCD-partitioned CSR build + weight transpose/convert ----
    hipMemsetAsync(cursor, 0, (size_t)NNODES * 4, stream);
    k_node_embed<<<(NNODES + 3) / 4, 256, 0, stream>>>(x, Wx, bx, h16);
    k_prep<<<(DEPTH * 8192 * 2) / 256, 256, 0, stream>>>(W1, W2, w1T, w2T);
    k_hist<<<(NEDGES / EPS) * 8, 256, 0, stream>>>(col, cursor);
    k_scan1<<<NB, 256, 0, stream>>>(cursor, bsum);
    k_scan2<<<1, 512, 0, stream>>>(bsum, boff);
    k_scan3<<<NB, 256, 0, stream>>>(cursor, boff, row_off);
    k_copy<<<NB, 256, 0, stream>>>(row_off, cursor);
    k_scatter<<<(NEDGES / EPS) * 8, 256, 0, stream>>>(row, col, cursor, sre);
    k_edge_embed<<<NEDGES / 256, 256, 0, stream>>>(eat, sre, We, be, eas, srow);

    // ---- layers ----
    const int msg_blocks = (NNODES + 3) / 4;
    const int mm_blocks = NNODES / 64;   // 1250, exact
    for (int l = 0; l < DEPTH; ++l) {
        k_msg<<<msg_blocks, 256, 0, stream>>>(h16, row_off, srow, eas, eps + l, zc16, bn_acc);
        k_gemm1<<<mm_blocks, 256, 0, stream>>>(zc16, w1T + (size_t)l * 8192,
                                               b1 + (size_t)l * HID2, z1, bn_acc);
        k_mlp2<<<mm_blocks, 256, 0, stream>>>(z1, bn_acc,
                                              g1 + (size_t)l * HID2, bt1 + (size_t)l * HID2,
                                              w2T + (size_t)l * 8192,
                                              b2 + (size_t)l * HID,
                                              lng + (size_t)l * HID, lnb + (size_t)l * HID,
                                              (l == DEPTH - 1) ? 1 : 0, h16, (float*)d_out);
    }
}

// Round 12
// 626.087 us; speedup vs baseline: 1.0036x; 1.0036x over previous
//
#include <hip/hip_runtime.h>
#include <cstdint>

typedef _Float16 half8 __attribute__((ext_vector_type(8)));
typedef float f32x4 __attribute__((ext_vector_type(4)));

#define NNODES 80000
#define NEDGES 1280000
#define INDIM 32
#define EDIM 16
#define HID 64
#define HID2 128
#define DEPTH 4
#define BN_EPS 1e-5f
#define LN_EPS 1e-5f
#define NB 313         // ceil(80000/256)
#define NPX 10000      // nodes per XCD partition (80000/8)
#define EPS 10000      // edges per slice (1280000/128)

union U16x8 { uint4 v; _Float16 h[8]; };
union U16x4 { uint2 v; _Float16 h[4]; };

// h = relu(x @ Wx + bx) -> f16; one wave per node, lane = out channel
__global__ __launch_bounds__(256) void k_node_embed(
    const float* __restrict__ x, const float* __restrict__ Wx,
    const float* __restrict__ bx, _Float16* __restrict__ h16) {
    int gw = (blockIdx.x * 256 + threadIdx.x) >> 6;
    int lane = threadIdx.x & 63;
    if (gw >= NNODES) return;
    float xv = (lane < INDIM) ? x[(size_t)gw * INDIM + lane] : 0.f;
    float acc = bx[lane];
#pragma unroll
    for (int k = 0; k < INDIM; k++)
        acc = fmaf(__shfl(xv, k, 64), Wx[k * HID + lane], acc);
    h16[(size_t)gw * HID + lane] = (_Float16)fmaxf(acc, 0.f);
}

// one-time: transpose+convert weights to f16. w1T[l][n(128)][k(64)], w2T[l][n(64)][k(128)]
__global__ __launch_bounds__(256) void k_prep(
    const float* __restrict__ W1, const float* __restrict__ W2,
    _Float16* __restrict__ w1T, _Float16* __restrict__ w2T) {
    int id = blockIdx.x * 256 + threadIdx.x;
    if (id < DEPTH * 128 * 64) {
        int l = id / 8192, r = id % 8192, n = r / 64, k = r % 64;
        w1T[id] = (_Float16)W1[(size_t)l * 8192 + k * 128 + n];
    } else {
        int idx = id - DEPTH * 128 * 64;
        int l = idx / 8192, r = idx % 8192, n = r / 128, k = r % 128;
        w2T[idx] = (_Float16)W2[(size_t)l * 8192 + k * 64 + n];
    }
}

// XCD-partitioned histogram: block s*8+r handles edge slice s, node range r.
__global__ __launch_bounds__(256) void k_hist(const int* __restrict__ col,
                                              int* __restrict__ deg) {
    int xcd = blockIdx.x & 7;
    int slice = blockIdx.x >> 3;
    int base = slice * EPS;
    int lo = xcd * NPX;
    const int4* c4 = (const int4*)(col + base);
    for (int i = threadIdx.x; i < EPS / 4; i += 256) {
        int4 c = c4[i];
#pragma unroll
        for (int u = 0; u < 4; u++) {
            int cc = (&c.x)[u];
            if ((unsigned)(cc - lo) < (unsigned)NPX) atomicAdd(&deg[cc], 1);
        }
    }
}

__global__ __launch_bounds__(256) void k_scan1(const int* __restrict__ deg, int* __restrict__ bsum) {
    __shared__ int s[256];
    int i = blockIdx.x * 256 + threadIdx.x;
    int v = (i < NNODES) ? deg[i] : 0;
    s[threadIdx.x] = v;
    __syncthreads();
    for (int o = 128; o > 0; o >>= 1) {
        if (threadIdx.x < o) s[threadIdx.x] += s[threadIdx.x + o];
        __syncthreads();
    }
    if (threadIdx.x == 0) bsum[blockIdx.x] = s[0];
}

__global__ __launch_bounds__(512) void k_scan2(const int* __restrict__ bsum, int* __restrict__ boff) {
    __shared__ int s[512];
    int t = threadIdx.x;
    s[t] = (t < NB) ? bsum[t] : 0;
    __syncthreads();
    for (int o = 1; o < 512; o <<= 1) {
        int v = (t >= o) ? s[t - o] : 0;
        __syncthreads();
        s[t] += v;
        __syncthreads();
    }
    if (t < NB) boff[t] = (t == 0) ? 0 : s[t - 1];
}

// scan3 writes BOTH row_off and cursor (deg slot is dead after the staged read),
// deleting the former k_copy kernel.
__global__ __launch_bounds__(256) void k_scan3(int* __restrict__ deg_cursor,
                                               const int* __restrict__ boff,
                                               int* __restrict__ row_off) {
    __shared__ int s[256];
    int i = blockIdx.x * 256 + threadIdx.x;
    int t = threadIdx.x;
    int v = (i < NNODES) ? deg_cursor[i] : 0;
    s[t] = v;
    __syncthreads();
    for (int o = 1; o < 256; o <<= 1) {
        int u = (t >= o) ? s[t - o] : 0;
        __syncthreads();
        s[t] += u;
        __syncthreads();
    }
    int incl = s[t];
    if (i < NNODES) {
        int excl = boff[blockIdx.x] + incl - v;
        row_off[i] = excl;
        deg_cursor[i] = excl;   // cursor initialized for k_scatter
    }
    if (i == NNODES - 1) row_off[NNODES] = boff[blockIdx.x] + incl;
}

// XCD-partitioned scatter: cursor atomics and sre line writes stay XCD-local.
__global__ __launch_bounds__(256) void k_scatter(
    const int* __restrict__ row, const int* __restrict__ col,
    int* __restrict__ cursor, uint2* __restrict__ sre) {
    int xcd = blockIdx.x & 7;
    int slice = blockIdx.x >> 3;
    int base = slice * EPS;
    int lo = xcd * NPX;
    const int4* c4 = (const int4*)(col + base);
    for (int i = threadIdx.x; i < EPS / 4; i += 256) {
        int4 c = c4[i];
        int e0 = base + i * 4;
#pragma unroll
        for (int u = 0; u < 4; u++) {
            int cc = (&c.x)[u];
            if ((unsigned)(cc - lo) < (unsigned)NPX) {
                int e = e0 + u;
                int pos = atomicAdd(&cursor[cc], 1);
                sre[pos] = make_uint2((unsigned)row[e], (unsigned)e);
            }
        }
    }
}

// ea[pos] = relu(edge_attr[sre[pos].y] @ We + be), f16, CSR order. Also emits srow.
// MFMA with SWAPPED operands: D = We_frag x edge_frag -> lane holds 4 CONTIGUOUS
// channels of one edge -> packed 8B direct-global stores. No O-transpose phase.
__global__ __launch_bounds__(256) void k_edge_embed(
    const float* __restrict__ eat, const uint2* __restrict__ sre,
    const float* __restrict__ We, const float* __restrict__ be,
    _Float16* __restrict__ eas, int* __restrict__ srow) {
    __shared__ __align__(16) unsigned char lds[4][5120];   // 64 edges x 80B per wave
    int tid = threadIdx.x;
    int w = tid >> 6, lane = tid & 63;
    unsigned char* A = lds[w];
    int ebase = blockIdx.x * 256 + w * 64;
    int b = lane >> 4, c = lane & 15;
    // We fragments (A operand: rows = channels t*16+c, k-octet b; zero for b>=2)
    half8 wf[4];
#pragma unroll
    for (int t = 0; t < 4; t++) {
        half8 v = {};
        if (b < 2) {
#pragma unroll
            for (int j = 0; j < 8; j++) {
                int k = b * 8 + j;
                v[j] = (_Float16)We[k * HID + t * 16 + c];
            }
        }
        wf[t] = v;
    }
    float4 bias4[4];
#pragma unroll
    for (int t = 0; t < 4; t++) bias4[t] = *(const float4*)(be + t * 16 + b * 4);
    uint2 se = sre[ebase + lane];
    srow[ebase + lane] = (int)se.x;
    const float4* ar = (const float4*)(eat + (size_t)se.y * EDIM);
    float4 a0 = ar[0], a1 = ar[1], a2 = ar[2], a3 = ar[3];
    U16x8 lo, hi;
    lo.h[0] = (_Float16)a0.x; lo.h[1] = (_Float16)a0.y;
    lo.h[2] = (_Float16)a0.z; lo.h[3] = (_Float16)a0.w;
    lo.h[4] = (_Float16)a1.x; lo.h[5] = (_Float16)a1.y;
    lo.h[6] = (_Float16)a1.z; lo.h[7] = (_Float16)a1.w;
    hi.h[0] = (_Float16)a2.x; hi.h[1] = (_Float16)a2.y;
    hi.h[2] = (_Float16)a2.z; hi.h[3] = (_Float16)a2.w;
    hi.h[4] = (_Float16)a3.x; hi.h[5] = (_Float16)a3.y;
    hi.h[6] = (_Float16)a3.z; hi.h[7] = (_Float16)a3.w;
    *(uint4*)(A + lane * 80) = lo.v;
    *(uint4*)(A + lane * 80 + 16) = hi.v;
    __syncthreads();
    half8 ef[4];
#pragma unroll
    for (int it = 0; it < 4; it++) {
        half8 z = {};
        ef[it] = (b < 2) ? *(const half8*)(A + (it * 16 + c) * 80 + b * 16) : z;
    }
#pragma unroll
    for (int it = 0; it < 4; it++) {
        int edge = ebase + it * 16 + c;
        _Float16* dst = eas + (size_t)edge * HID + b * 4;
#pragma unroll
        for (int t = 0; t < 4; t++) {
            f32x4 acc = {0.f, 0.f, 0.f, 0.f};
            acc = __builtin_amdgcn_mfma_f32_16x16x32_f16(wf[t], ef[it], acc, 0, 0, 0);
            U16x4 pk;
#pragma unroll
            for (int r = 0; r < 4; r++)
                pk.h[r] = (_Float16)fmaxf(acc[r] + ((const float*)&bias4[t])[r], 0.f);
            *(uint2*)(dst + t * 16) = pk.v;
        }
    }
}

// zc[i] = (1+eps)*h[i] + sum_e relu(h[srow[e]] + ea[e]); vectorized:
// lane = (edge-slot = lane>>3, channel-octet = (lane&7)*8), uint4 loads
// -> 8 edges per VMEM instruction. Also zeroes bn_acc (block 0).
__global__ __launch_bounds__(256) void k_msg(
    const _Float16* __restrict__ h16, const int* __restrict__ row_off,
    const int* __restrict__ srow, const _Float16* __restrict__ eas,
    const float* __restrict__ epsp, _Float16* __restrict__ zc16,
    float* __restrict__ bn_acc) {
    if (blockIdx.x == 0) bn_acc[threadIdx.x] = 0.f;
    int gw = (blockIdx.x * 256 + threadIdx.x) >> 6;
    int lane = threadIdx.x & 63;
    if (gw >= NNODES) return;
    int grp = lane >> 3;          // edge slot 0..7
    int c8 = (lane & 7) * 8;      // channel octet base
    int beg = row_off[gw], end = row_off[gw + 1];
    float a[8] = {0.f, 0.f, 0.f, 0.f, 0.f, 0.f, 0.f, 0.f};
    int e = beg;
    for (; e + 16 <= end; e += 16) {
        int e0 = e + grp, e1 = e + 8 + grp;
        int j0 = srow[e0], j1 = srow[e1];
        U16x8 hv0, ev0, hv1, ev1;
        hv0.v = *(const uint4*)(h16 + (size_t)j0 * HID + c8);
        ev0.v = *(const uint4*)(eas + (size_t)e0 * HID + c8);
        hv1.v = *(const uint4*)(h16 + (size_t)j1 * HID + c8);
        ev1.v = *(const uint4*)(eas + (size_t)e1 * HID + c8);
#pragma unroll
        for (int q = 0; q < 8; q++) {
            a[q] += fmaxf((float)hv0.h[q] + (float)ev0.h[q], 0.f) +
                    fmaxf((float)hv1.h[q] + (float)ev1.h[q], 0.f);
        }
    }
    for (; e + 8 <= end; e += 8) {
        int e0 = e + grp;
        int j0 = srow[e0];
        U16x8 hv0, ev0;
        hv0.v = *(const uint4*)(h16 + (size_t)j0 * HID + c8);
        ev0.v = *(const uint4*)(eas + (size_t)e0 * HID + c8);
#pragma unroll
        for (int q = 0; q < 8; q++)
            a[q] += fmaxf((float)hv0.h[q] + (float)ev0.h[q], 0.f);
    }
    if (e < end) {   // tail 1..7 edges, masked
        int eidx = e + grp;
        bool valid = eidx < end;
        int ec = valid ? eidx : (NEDGES - 1);
        int j = srow[ec];
        U16x8 hv, ev;
        hv.v = *(const uint4*)(h16 + (size_t)j * HID + c8);
        ev.v = *(const uint4*)(eas + (size_t)ec * HID + c8);
        if (valid) {
#pragma unroll
            for (int q = 0; q < 8; q++)
                a[q] += fmaxf((float)hv.h[q] + (float)ev.h[q], 0.f);
        }
    }
#pragma unroll
    for (int q = 0; q < 8; q++) {
        a[q] += __shfl_xor(a[q], 8, 64);
        a[q] += __shfl_xor(a[q], 16, 64);
        a[q] += __shfl_xor(a[q], 32, 64);
    }
    if (grp == 0) {
        float epsl = 1.f + *epsp;
        U16x8 h0, o;
        h0.v = *(const uint4*)(h16 + (size_t)gw * HID + c8);
#pragma unroll
        for (int q = 0; q < 8; q++)
            o.h[q] = (_Float16)(epsl * (float)h0.h[q] + a[q]);
        *(uint4*)(zc16 + (size_t)gw * HID + c8) = o.v;
    }
}

// MFMA GEMM1: z1 = zc @ W1 + b1 (f16 in, f16 out) + BN sum/sumsq accumulation.
__global__ __launch_bounds__(256) void k_gemm1(
    const _Float16* __restrict__ zc16, const _Float16* __restrict__ w1Tl,
    const float* __restrict__ b1l, _Float16* __restrict__ z1,
    float* __restrict__ bn_acc) {
    __shared__ __align__(16) unsigned char At[64 * 128];    // 64 nodes x 64 f16, swizzled
    __shared__ __align__(16) unsigned char Bt[128 * 128];   // 128 cols x 64 f16, swizzled
    __shared__ float red[4][HID2][2];
    int tid = threadIdx.x;
    int nb = blockIdx.x * 64;
#pragma unroll
    for (int i = 0; i < 2; i++) {
        int id = tid + 256 * i;
        int node = id >> 3, c = id & 7;
        uint4 v = *(const uint4*)(zc16 + (size_t)(nb + node) * HID + c * 8);
        *(uint4*)(At + node * 128 + ((c ^ (node & 7)) << 4)) = v;
    }
#pragma unroll
    for (int i = 0; i < 4; i++) {
        int id = tid + 256 * i;
        int r = id >> 3, c = id & 7;
        uint4 v = *(const uint4*)(w1Tl + (size_t)r * HID + c * 8);
        *(uint4*)(Bt + r * 128 + ((c ^ (r & 7)) << 4)) = v;
    }
    __syncthreads();
    int lane = tid & 63, w = tid >> 6;
    int rl = lane & 15, b = lane >> 4;
    f32x4 acc[8];
#pragma unroll
    for (int t = 0; t < 8; t++) acc[t] = (f32x4){0.f, 0.f, 0.f, 0.f};
#pragma unroll
    for (int s = 0; s < 2; s++) {
        int arow = w * 16 + rl;
        half8 af = *(const half8*)(At + arow * 128 + (((s * 4 + b) ^ (rl & 7)) << 4));
#pragma unroll
        for (int t = 0; t < 8; t++) {
            int brow = t * 16 + rl;
            half8 bf = *(const half8*)(Bt + brow * 128 + (((s * 4 + b) ^ (rl & 7)) << 4));
            acc[t] = __builtin_amdgcn_mfma_f32_16x16x32_f16(af, bf, acc[t], 0, 0, 0);
        }
    }
#pragma unroll
    for (int t = 0; t < 8; t++) {
        int colg = t * 16 + rl;
        float bias = b1l[colg];
        float s = 0.f, q = 0.f;
#pragma unroll
        for (int r = 0; r < 4; r++) {
            float v = acc[t][r] + bias;
            int node = nb + w * 16 + b * 4 + r;
            z1[(size_t)node * HID2 + colg] = (_Float16)v;
            s += v;
            q = fmaf(v, v, q);
        }
        s += __shfl_xor(s, 16, 64); s += __shfl_xor(s, 32, 64);
        q += __shfl_xor(q, 16, 64); q += __shfl_xor(q, 32, 64);
        if (b == 0) { red[w][colg][0] = s; red[w][colg][1] = q; }
    }
    __syncthreads();
    int ch = tid & 127, which = tid >> 7;
    float tot = red[0][ch][which] + red[1][ch][which] + red[2][ch][which] + red[3][ch][which];
    atomicAdd(&bn_acc[which * HID2 + ch], tot);
}

// MFMA GEMM2 with inlined BN finalize: y = relu(BN(z1)); out = LN(y @ W2 + b2).
__global__ __launch_bounds__(256) void k_mlp2(
    const _Float16* __restrict__ z1, const float* __restrict__ bn_acc,
    const float* __restrict__ g1l, const float* __restrict__ bt1l,
    const _Float16* __restrict__ w2Tl, const float* __restrict__ b2l,
    const float* __restrict__ lngl, const float* __restrict__ lnbl,
    int last, _Float16* __restrict__ hout, float* __restrict__ fout) {
    __shared__ __align__(16) unsigned char Yt[64 * 256];   // 64 nodes x 128 f16, swizzled
    __shared__ __align__(16) unsigned char Wt[64 * 256];   // 64 cols x 128 f16, swizzled
    __shared__ float sbn[256];
    int tid = threadIdx.x;
    int nb = blockIdx.x * 64;
    if (tid < HID2) {   // inline BN finalize
        float inv_n = 1.f / (float)NNODES;
        float mu = bn_acc[tid] * inv_n;
        float ex2 = bn_acc[HID2 + tid] * inv_n;
        float rs = rsqrtf(ex2 - mu * mu + BN_EPS);
        float sc = g1l[tid] * rs;
        sbn[tid] = sc;
        sbn[HID2 + tid] = bt1l[tid] - mu * sc;
    }
#pragma unroll
    for (int i = 0; i < 4; i++) {
        int id = tid + 256 * i;
        int r = id >> 4, c = id & 15;
        uint4 v = *(const uint4*)(w2Tl + (size_t)r * HID2 + c * 8);
        *(uint4*)(Wt + r * 256 + ((c ^ (r & 7)) << 4)) = v;
    }
    __syncthreads();
#pragma unroll
    for (int i = 0; i < 4; i++) {
        int id = tid + 256 * i;
        int node = id >> 4, c = id & 15;
        U16x8 u, o;
        u.v = *(const uint4*)(z1 + (size_t)(nb + node) * HID2 + c * 8);
#pragma unroll
        for (int j = 0; j < 8; j++) {
            int chn = c * 8 + j;
            float y = fmaxf(fmaf((float)u.h[j], sbn[chn], sbn[HID2 + chn]), 0.f);
            o.h[j] = (_Float16)y;
        }
        *(uint4*)(Yt + node * 256 + ((c ^ (node & 7)) << 4)) = o.v;
    }
    __syncthreads();
    int lane = tid & 63, w = tid >> 6;
    int rl = lane & 15, b = lane >> 4;
    f32x4 acc[4];
#pragma unroll
    for (int t = 0; t < 4; t++) acc[t] = (f32x4){0.f, 0.f, 0.f, 0.f};
#pragma unroll
    for (int s = 0; s < 4; s++) {
        int arow = w * 16 + rl;
        half8 af = *(const half8*)(Yt + arow * 256 + (((s * 4 + b) ^ (rl & 7)) << 4));
#pragma unroll
        for (int t = 0; t < 4; t++) {
            int brow = t * 16 + rl;
            half8 bf = *(const half8*)(Wt + brow * 256 + (((s * 4 + b) ^ (rl & 7)) << 4));
            acc[t] = __builtin_amdgcn_mfma_f32_16x16x32_f16(af, bf, acc[t], 0, 0, 0);
        }
    }
    float a[4][4]; // [r][t]
#pragma unroll
    for (int t = 0; t < 4; t++) {
        float bias = b2l[t * 16 + rl];
#pragma unroll
        for (int r = 0; r < 4; r++) a[r][t] = acc[t][r] + bias;
    }
    float m[4], vv[4];
#pragma unroll
    for (int r = 0; r < 4; r++) {
        float s = (a[r][0] + a[r][1]) + (a[r][2] + a[r][3]);
        s += __shfl_xor(s, 1, 64); s += __shfl_xor(s, 2, 64);
        s += __shfl_xor(s, 4, 64); s += __shfl_xor(s, 8, 64);
        m[r] = s * (1.f / 64.f);
    }
#pragma unroll
    for (int r = 0; r < 4; r++) {
        float t0 = a[r][0] - m[r], t1 = a[r][1] - m[r];
        float t2 = a[r][2] - m[r], t3 = a[r][3] - m[r];
        float q = (t0 * t0 + t1 * t1) + (t2 * t2 + t3 * t3);
        q += __shfl_xor(q, 1, 64); q += __shfl_xor(q, 2, 64);
        q += __shfl_xor(q, 4, 64); q += __shfl_xor(q, 8, 64);
        vv[r] = rsqrtf(q * (1.f / 64.f) + LN_EPS);
    }
#pragma unroll
    for (int t = 0; t < 4; t++) {
        int colg = t * 16 + rl;
        float lg = lngl[colg], lb = lnbl[colg];
#pragma unroll
        for (int r = 0; r < 4; r++) {
            float o = (a[r][t] - m[r]) * vv[r] * lg + lb;
            size_t node = nb + w * 16 + b * 4 + r;
            if (last) {
                fout[node * HID + colg] = o;
            } else {
                hout[node * HID + colg] = (_Float16)fmaxf(o, 0.f);
            }
        }
    }
}

extern "C" void kernel_launch(void* const* d_in, const int* in_sizes, int n_in,
                              void* d_out, int out_size, void* d_ws, size_t ws_size,
                              hipStream_t stream) {
    const float* x   = (const float*)d_in[0];
    const int*   ei  = (const int*)d_in[1];
    const float* eat = (const float*)d_in[2];
    const float* Wx  = (const float*)d_in[3];
    const float* bx  = (const float*)d_in[4];
    const float* We  = (const float*)d_in[5];
    const float* be  = (const float*)d_in[6];
    const float* W1  = (const float*)d_in[7];
    const float* b1  = (const float*)d_in[8];
    const float* g1  = (const float*)d_in[9];
    const float* bt1 = (const float*)d_in[10];
    const float* W2  = (const float*)d_in[11];
    const float* b2  = (const float*)d_in[12];
    const float* eps = (const float*)d_in[13];
    const float* lng = (const float*)d_in[14];
    const float* lnb = (const float*)d_in[15];
    const int* row = ei;
    const int* col = ei + NEDGES;

    char* p = (char*)d_ws;
    auto alloc = [&](size_t bytes) -> char* {
        char* r = p;
        p += (bytes + 255) & ~(size_t)255;
        return r;
    };
    _Float16* h16  = (_Float16*)alloc((size_t)NNODES * HID * 2);
    _Float16* zc16 = (_Float16*)alloc((size_t)NNODES * HID * 2);
    _Float16* z1   = (_Float16*)alloc((size_t)NNODES * HID2 * 2);
    int* row_off   = (int*)alloc((size_t)(NNODES + 1) * 4);
    uint2* sre     = (uint2*)alloc((size_t)NEDGES * 8);
    int* srow      = (int*)alloc((size_t)NEDGES * 4);
    _Float16* eas  = (_Float16*)alloc((size_t)NEDGES * HID * 2);
    _Float16* w1T  = (_Float16*)alloc((size_t)DEPTH * 128 * 64 * 2);
    _Float16* w2T  = (_Float16*)alloc((size_t)DEPTH * 64 * 128 * 2);
    float* bn_acc  = (float*)alloc(256 * 4);
    // preamble-only buffers overlaid into z1's region (z1 first written in layer loop)
    int* cursor = (int*)z1;                       // NNODES ints
    int* bsum   = (int*)z1 + NNODES;              // NB ints
    int* boff   = bsum + NB;                      // NB ints
    (void)ws_size; (void)in_sizes; (void)n_in; (void)out_size;

    // ---- one-time: embeds + XCD-partitioned CSR build + weight transpose/convert ----
    hipMemsetAsync(cursor, 0, (size_t)NNODES * 4, stream);
    k_node_embed<<<(NNODES + 3) / 4, 256, 0, stream>>>(x, Wx, bx, h16);
    k_prep<<<(DEPTH * 8192 * 2) / 256, 256, 0, stream>>>(W1, W2, w1T, w2T);
    k_hist<<<(NEDGES / EPS) * 8, 256, 0, stream>>>(col, cursor);
    k_scan1<<<NB, 256, 0, stream>>>(cursor, bsum);
    k_scan2<<<1, 512, 0, stream>>>(bsum, boff);
    k_scan3<<<NB, 256, 0, stream>>>(cursor, boff, row_off);
    k_scatter<<<(NEDGES / EPS) * 8, 256, 0, stream>>>(row, col, cursor, sre);
    k_edge_embed<<<NEDGES / 256, 256, 0, stream>>>(eat, sre, We, be, eas, srow);

    // ---- layers ----
    const int msg_blocks = (NNODES + 3) / 4;
    const int mm_blocks = NNODES / 64;   // 1250, exact
    for (int l = 0; l < DEPTH; ++l) {
        k_msg<<<msg_blocks, 256, 0, stream>>>(h16, row_off, srow, eas, eps + l, zc16, bn_acc);
        k_gemm1<<<mm_blocks, 256, 0, stream>>>(zc16, w1T + (size_t)l * 8192,
                                               b1 + (size_t)l * HID2, z1, bn_acc);
        k_mlp2<<<mm_blocks, 256, 0, stream>>>(z1, bn_acc,
                                              g1 + (size_t)l * HID2, bt1 + (size_t)l * HID2,
                                              w2T + (size_t)l * 8192,
                                              b2 + (size_t)l * HID,
                                              lng + (size_t)l * HID, lnb + (size_t)l * HID,
                                              (l == DEPTH - 1) ? 1 : 0, h16, (float*)d_out);
    }
}